// Round 8
// baseline (287.239 us; speedup 1.0000x reference)
//
#include <hip/hip_runtime.h>
#include <math.h>

// Problem constants (from reference)
#define Bn   16
#define Cn   64
#define Nn   65536        // H*W = 256*256
#define Sn   32           // n-slices per batch (one slice per block)
#define Ln   (Nn / Sn)    // 2048 k-elements per slice (512 per wave)
#define REDn 16
#define GRID (Bn * Sn)    // 512 blocks (empirically launchable cooperatively)

typedef float    f32x4  __attribute__((ext_vector_type(4)));
typedef float    f32x16 __attribute__((ext_vector_type(16)));
typedef __fp16   fp16x2 __attribute__((ext_vector_type(2)));
typedef _Float16 f16x8  __attribute__((ext_vector_type(8)));

union half8_u {
  f16x8  v;
  fp16x2 h[4];
};

// ---------------------------------------------------------------------------
// Fused cooperative kernel with CUSTOM lightweight grid barriers.
//  phase 1: per-block gram+pool partials -> front of d_out (AGENT atomics)
//           arrive: fetch_add(cnt0)
//  phase 2: blocks 0..15 wait cnt0==512, reduce + MLP -> g (AGENT atomics)
//           arrive: fetch_add(cnt1)
//  phase 3: all blocks wait cnt1==16, stage g->LDS, out = x * g
//  (cooperative launch guarantees co-residency; grid.sync() never called)
// ---------------------------------------------------------------------------
__global__ __launch_bounds__(256, 2) void fused_kernel(
    const float* __restrict__ x, const float* __restrict__ Wrow,
    const float* __restrict__ brow,
    const float* __restrict__ W1, const float* __restrict__ b1,
    const float* __restrict__ W2, const float* __restrict__ b2,
    float* __restrict__ out, float* __restrict__ gbuf,
    unsigned* __restrict__ cnt) {
  const int bid  = blockIdx.x;
  const int b    = bid >> 5;        // batch
  const int s    = bid & 31;        // slice
  const int tid  = threadIdx.x;
  const int wid  = tid >> 6;
  const int lane = tid & 63;
  const int l31  = lane & 31;
  const int lhi  = lane >> 5;
  const int rr   = lane >> 2;       // staging row-within-group (0..15)
  const int cc   = lane & 3;        // staging 16B chunk (0..3)

  const float* xb = x + (size_t)b * Cn * Nn;

  __shared__ float stage[4][Cn * 17];   // per-wave [64 rows][17] f32 (pad)
  __shared__ float corr_s[Cn][Cn + 1];
  __shared__ float pool_lds0[4][32];
  __shared__ float pool_lds1[4][32];
  __shared__ float rs_s[4][Cn], rp_s[4][Cn];   // phase-2 reduction
  __shared__ float y_s[Cn];
  __shared__ float z_s[REDn];

  unsigned* cnt0 = cnt;
  unsigned* cnt1 = cnt + 16;

  // ======================= phase 1: gram + pool ============================
  {
    float* wb = &stage[wid][0];

    const float* gsrc[4];
    int widx[4];
#pragma unroll
    for (int i = 0; i < 4; ++i) {
      const int row = 16 * i + rr;
      gsrc[i] = xb + (size_t)row * Nn + cc * 4;
      widx[i] = row * 17 + cc * 4;
    }
    const int fA = l31 * 17 + lhi * 8;          // rows 0..31
    const int fB = (l31 + 32) * 17 + lhi * 8;   // rows 32..63

    const int kw = s * Ln + wid * (Ln / 4);     // wave's k base; 32 tiles of 16

    f32x16 acc00, acc01, acc11;
#pragma unroll
    for (int r = 0; r < 16; ++r) { acc00[r] = 0.f; acc01[r] = 0.f; acc11[r] = 0.f; }
    float pool0 = 0.f, pool1 = 0.f;

    f32x4 sA[4], sB[4];
#pragma unroll
    for (int i = 0; i < 4; ++i) sA[i] = *(const f32x4*)(gsrc[i] + kw);
#pragma unroll
    for (int i = 0; i < 4; ++i) sB[i] = *(const f32x4*)(gsrc[i] + kw + 16);

    auto step = [&](f32x4* stg, int t) {
#pragma unroll
      for (int i = 0; i < 4; ++i) *(f32x4*)&wb[widx[i]] = stg[i];
      if (t < 30) {
        const int ko = kw + (t + 2) * 16;
#pragma unroll
        for (int i = 0; i < 4; ++i) stg[i] = *(const f32x4*)(gsrc[i] + ko);
      }
      f32x4 a0 = *(const f32x4*)&wb[fA];
      f32x4 a1 = *(const f32x4*)&wb[fA + 4];
      f32x4 c0 = *(const f32x4*)&wb[fB];
      f32x4 c1 = *(const f32x4*)&wb[fB + 4];

      pool0 += (a0[0] + a0[1]) + (a0[2] + a0[3]) + (a1[0] + a1[1]) + (a1[2] + a1[3]);
      pool1 += (c0[0] + c0[1]) + (c0[2] + c0[3]) + (c1[0] + c1[1]) + (c1[2] + c1[3]);

      half8_u au, bu;
      au.h[0] = __builtin_amdgcn_cvt_pkrtz(a0[0], a0[1]);
      au.h[1] = __builtin_amdgcn_cvt_pkrtz(a0[2], a0[3]);
      au.h[2] = __builtin_amdgcn_cvt_pkrtz(a1[0], a1[1]);
      au.h[3] = __builtin_amdgcn_cvt_pkrtz(a1[2], a1[3]);
      bu.h[0] = __builtin_amdgcn_cvt_pkrtz(c0[0], c0[1]);
      bu.h[1] = __builtin_amdgcn_cvt_pkrtz(c0[2], c0[3]);
      bu.h[2] = __builtin_amdgcn_cvt_pkrtz(c1[0], c1[1]);
      bu.h[3] = __builtin_amdgcn_cvt_pkrtz(c1[2], c1[3]);

      acc00 = __builtin_amdgcn_mfma_f32_32x32x16_f16(au.v, au.v, acc00, 0, 0, 0);
      acc01 = __builtin_amdgcn_mfma_f32_32x32x16_f16(au.v, bu.v, acc01, 0, 0, 0);
      acc11 = __builtin_amdgcn_mfma_f32_32x32x16_f16(bu.v, bu.v, acc11, 0, 0, 0);
    };

#pragma unroll
    for (int tp = 0; tp < 16; ++tp) {
      step(sA, 2 * tp);
      step(sB, 2 * tp + 1);
    }

    pool0 += __shfl_down(pool0, 32);
    pool1 += __shfl_down(pool1, 32);
    if (lane < 32) {
      pool_lds0[wid][lane] = pool0;
      pool_lds1[wid][lane] = pool1;
    }

    for (int w = 0; w < 4; ++w) {
      __syncthreads();
      if (wid == w) {
#pragma unroll
        for (int r = 0; r < 16; ++r) {
          // verified C/D layout (32x32 MFMA): col=lane&31, row=(r&3)+8*(r>>2)+4*(lane>>5)
          const int i = (r & 3) + 8 * (r >> 2) + 4 * lhi;
          const int j = l31;
          if (w == 0) {
            corr_s[i][j]           = acc00[r];
            corr_s[i][j + 32]      = acc01[r];
            corr_s[j + 32][i]      = acc01[r];   // symmetric mirror
            corr_s[i + 32][j + 32] = acc11[r];
          } else {
            corr_s[i][j]           += acc00[r];
            corr_s[i][j + 32]      += acc01[r];
            corr_s[j + 32][i]      += acc01[r];
            corr_s[i + 32][j + 32] += acc11[r];
          }
        }
      }
    }
    __syncthreads();

    if (tid < Cn) {
      const float* wr = Wrow + tid * Cn;
      float so = 0.f;
#pragma unroll 8
      for (int d = 0; d < Cn; ++d) so += corr_s[tid][d] * wr[d];
      float pp = 0.f;
      if (tid < 32) {
#pragma unroll
        for (int w = 0; w < 4; ++w) pp += pool_lds0[w][tid];
      } else {
#pragma unroll
        for (int w = 0; w < 4; ++w) pp += pool_lds1[w][tid - 32];
      }
      float* o = out + (size_t)bid * (2 * Cn);   // partials in front of d_out
      __hip_atomic_store(&o[tid],      so, __ATOMIC_RELAXED, __HIP_MEMORY_SCOPE_AGENT);
      __hip_atomic_store(&o[Cn + tid], pp, __ATOMIC_RELAXED, __HIP_MEMORY_SCOPE_AGENT);
    }
  }

  // arrive: syncthreads drains vmcnt per wave before barrier, so the atomic
  // stores above are globally visible before the counter bump.
  __syncthreads();
  if (tid == 0)
    __hip_atomic_fetch_add(cnt0, 1u, __ATOMIC_ACQ_REL, __HIP_MEMORY_SCOPE_AGENT);

  // ======================= phase 2: gate g (blocks 0..15) ==================
  if (bid < Bn) {
    if (tid == 0) {
      while (__hip_atomic_load(cnt0, __ATOMIC_ACQUIRE, __HIP_MEMORY_SCOPE_AGENT) < GRID)
        __builtin_amdgcn_s_sleep(2);
    }
    __syncthreads();

    const int c = tid & 63;
    const int q = tid >> 6;
    float so = 0.f, pl = 0.f;
    for (int ss = q * 8; ss < q * 8 + 8; ++ss) {
      const float* p = out + (size_t)(bid * Sn + ss) * (2 * Cn);
      so += __hip_atomic_load(&p[c],      __ATOMIC_RELAXED, __HIP_MEMORY_SCOPE_AGENT);
      pl += __hip_atomic_load(&p[Cn + c], __ATOMIC_RELAXED, __HIP_MEMORY_SCOPE_AGENT);
    }
    rs_s[q][c] = so;
    rp_s[q][c] = pl;
    __syncthreads();
    if (tid < Cn) {
      so = rs_s[0][tid] + rs_s[1][tid] + rs_s[2][tid] + rs_s[3][tid];
      pl = rp_s[0][tid] + rp_s[1][tid] + rp_s[2][tid] + rp_s[3][tid];
      y_s[tid] = (so + pl) * (1.0f / (float)Nn) + brow[tid];
    }
    __syncthreads();
    if (tid < REDn) {
      float z = b1[tid];
#pragma unroll 8
      for (int c2 = 0; c2 < Cn; ++c2) z += W1[tid * Cn + c2] * y_s[c2];
      z_s[tid] = fmaxf(z, 0.f);
    }
    __syncthreads();
    if (tid < Cn) {
      float a = b2[tid];
#pragma unroll
      for (int r = 0; r < REDn; ++r) a += W2[tid * REDn + r] * z_s[r];
      const float gate = 1.0f / (1.0f + expf(-a));
      __hip_atomic_store(&gbuf[bid * Cn + tid], gate,
                         __ATOMIC_RELAXED, __HIP_MEMORY_SCOPE_AGENT);
    }
    __syncthreads();   // drain the g stores (vmcnt) before arriving
    if (tid == 0)
      __hip_atomic_fetch_add(cnt1, 1u, __ATOMIC_ACQ_REL, __HIP_MEMORY_SCOPE_AGENT);
  }

  // ======================= phase 3: out = x * g ============================
  {
    if (tid == 0) {
      while (__hip_atomic_load(cnt1, __ATOMIC_ACQUIRE, __HIP_MEMORY_SCOPE_AGENT) < Bn)
        __builtin_amdgcn_s_sleep(2);
    }
    __syncthreads();

    // stage g into LDS (overlay on dead staging buffer)
    float* g_lds = &stage[0][0];
    for (int i = tid; i < Bn * Cn; i += 256)
      g_lds[i] = __hip_atomic_load(&gbuf[i], __ATOMIC_RELAXED, __HIP_MEMORY_SCOPE_AGENT);
    __syncthreads();

    const f32x4* xv = (const f32x4*)x;
    f32x4*       ov = (f32x4*)out;
    const size_t stride = (size_t)GRID * 256;          // 131072 threads
    const size_t base   = (size_t)bid * 256 + tid;
    const int    gbase  = (int)(base >> 14);
    // total float4 = 16777216 = 128 * stride; 4 loads in flight per lane
#pragma unroll 1
    for (int it = 0; it < 32; ++it) {
      const size_t i0 = base + (size_t)(4 * it) * stride;
      const int    g0 = gbase + 32 * it;   // (i0 + u*stride)>>14 == g0 + 8u (exact)
      f32x4 v0 = xv[i0];
      f32x4 v1 = xv[i0 + stride];
      f32x4 v2 = xv[i0 + 2 * stride];
      f32x4 v3 = xv[i0 + 3 * stride];
      v0 *= g_lds[g0];
      v1 *= g_lds[g0 + 8];
      v2 *= g_lds[g0 + 16];
      v3 *= g_lds[g0 + 24];
      ov[i0]              = v0;
      ov[i0 + stride]     = v1;
      ov[i0 + 2 * stride] = v2;
      ov[i0 + 3 * stride] = v3;
    }
  }
}

// ---------------------------------------------------------------------------
extern "C" void kernel_launch(void* const* d_in, const int* in_sizes, int n_in,
                              void* d_out, int out_size, void* d_ws, size_t ws_size,
                              hipStream_t stream) {
  const float* x    = (const float*)d_in[0];
  const float* Wrow = (const float*)d_in[1];
  const float* brow = (const float*)d_in[2];
  const float* W1   = (const float*)d_in[3];
  const float* b1   = (const float*)d_in[4];
  const float* W2   = (const float*)d_in[5];
  const float* b2   = (const float*)d_in[6];
  float* out = (float*)d_out;

  // d_ws layout: [0,4096) gate g (16*64 f32); [4096,4096+128) barrier counters
  float*    gbuf = (float*)d_ws;
  unsigned* cnt  = (unsigned*)((char*)d_ws + 4096);

  // zero the barrier counters every call (deterministic; capture-safe)
  hipMemsetAsync((void*)cnt, 0, 128, stream);

  void* args[] = {(void*)&x, (void*)&Wrow, (void*)&brow, (void*)&W1,
                  (void*)&b1, (void*)&W2, (void*)&b2, (void*)&out,
                  (void*)&gbuf, (void*)&cnt};
  hipLaunchCooperativeKernel((void*)fused_kernel, dim3(GRID), dim3(256),
                             args, 0, stream);
}

// Round 10
// 158.476 us; speedup vs baseline: 1.8125x; 1.8125x over previous
//
#include <hip/hip_runtime.h>
#include <math.h>

// Problem constants (from reference)
#define Bn   16
#define Cn   64
#define Nn   65536        // H*W = 256*256
#define Sn   64           // n-slices per batch for gram kernel
#define Ln   (Nn / Sn)    // 1024 k-elements per block (256 per wave)
#define REDn 16

typedef float    f32x4  __attribute__((ext_vector_type(4)));
typedef float    f32x16 __attribute__((ext_vector_type(16)));
typedef __fp16   fp16x2 __attribute__((ext_vector_type(2)));
typedef _Float16 f16x8  __attribute__((ext_vector_type(8)));

union half8_u {
  f16x8  v;
  fp16x2 h[4];
};

// ---------------------------------------------------------------------------
// Kernel 1: per (batch, n-slice) block:
//   so_part[c]   = sum_d (sum_{n in slice} x[b,c,n]*x[b,d,n]) * Wrow[c,d]
//   pool_part[c] = sum_{n in slice} x[b,c,n]
// Coalesced global loads into WAVE-PRIVATE LDS buffers (no main-loop barriers),
// 2-tile register prefetch; MFMA fragments via padded conflict-free ds_read.
// (Proven correct+fast in R5.)
// ---------------------------------------------------------------------------
__global__ __launch_bounds__(256, 4) void gram_pool_kernel(
    const float* __restrict__ x, const float* __restrict__ Wrow,
    float* __restrict__ part) {
  const int b    = blockIdx.x / Sn;
  const int s    = blockIdx.x % Sn;
  const int tid  = threadIdx.x;
  const int wid  = tid >> 6;
  const int lane = tid & 63;
  const int l31  = lane & 31;
  const int lhi  = lane >> 5;
  const int rr   = lane >> 2;   // staging row-within-group (0..15)
  const int cc   = lane & 3;    // staging 16B chunk (0..3)

  const float* xb = x + (size_t)b * Cn * Nn;

  __shared__ float stage[4][Cn * 17];   // per-wave [64 rows][17] f32 (pad)
  __shared__ float corr_s[Cn][Cn + 1];
  __shared__ float pool_lds0[4][32];
  __shared__ float pool_lds1[4][32];

  float* wb = &stage[wid][0];

  const float* gsrc[4];
  int widx[4];
#pragma unroll
  for (int i = 0; i < 4; ++i) {
    const int row = 16 * i + rr;
    gsrc[i] = xb + (size_t)row * Nn + cc * 4;
    widx[i] = row * 17 + cc * 4;
  }
  const int fA = l31 * 17 + lhi * 8;          // rows 0..31
  const int fB = (l31 + 32) * 17 + lhi * 8;   // rows 32..63

  const int kw = s * Ln + wid * (Ln / 4);     // wave's k base; 16 tiles of 16

  f32x16 acc00, acc01, acc11;
#pragma unroll
  for (int r = 0; r < 16; ++r) { acc00[r] = 0.f; acc01[r] = 0.f; acc11[r] = 0.f; }
  float pool0 = 0.f, pool1 = 0.f;

  f32x4 sA[4], sB[4];
#pragma unroll
  for (int i = 0; i < 4; ++i) sA[i] = *(const f32x4*)(gsrc[i] + kw);
#pragma unroll
  for (int i = 0; i < 4; ++i) sB[i] = *(const f32x4*)(gsrc[i] + kw + 16);

  auto step = [&](f32x4* stg, int t) {
#pragma unroll
    for (int i = 0; i < 4; ++i) *(f32x4*)&wb[widx[i]] = stg[i];
    if (t < 14) {
      const int ko = kw + (t + 2) * 16;
#pragma unroll
      for (int i = 0; i < 4; ++i) stg[i] = *(const f32x4*)(gsrc[i] + ko);
    }
    f32x4 a0 = *(const f32x4*)&wb[fA];
    f32x4 a1 = *(const f32x4*)&wb[fA + 4];
    f32x4 c0 = *(const f32x4*)&wb[fB];
    f32x4 c1 = *(const f32x4*)&wb[fB + 4];

    pool0 += (a0[0] + a0[1]) + (a0[2] + a0[3]) + (a1[0] + a1[1]) + (a1[2] + a1[3]);
    pool1 += (c0[0] + c0[1]) + (c0[2] + c0[3]) + (c1[0] + c1[1]) + (c1[2] + c1[3]);

    half8_u au, bu;
    au.h[0] = __builtin_amdgcn_cvt_pkrtz(a0[0], a0[1]);
    au.h[1] = __builtin_amdgcn_cvt_pkrtz(a0[2], a0[3]);
    au.h[2] = __builtin_amdgcn_cvt_pkrtz(a1[0], a1[1]);
    au.h[3] = __builtin_amdgcn_cvt_pkrtz(a1[2], a1[3]);
    bu.h[0] = __builtin_amdgcn_cvt_pkrtz(c0[0], c0[1]);
    bu.h[1] = __builtin_amdgcn_cvt_pkrtz(c0[2], c0[3]);
    bu.h[2] = __builtin_amdgcn_cvt_pkrtz(c1[0], c1[1]);
    bu.h[3] = __builtin_amdgcn_cvt_pkrtz(c1[2], c1[3]);

    acc00 = __builtin_amdgcn_mfma_f32_32x32x16_f16(au.v, au.v, acc00, 0, 0, 0);
    acc01 = __builtin_amdgcn_mfma_f32_32x32x16_f16(au.v, bu.v, acc01, 0, 0, 0);
    acc11 = __builtin_amdgcn_mfma_f32_32x32x16_f16(bu.v, bu.v, acc11, 0, 0, 0);
  };

#pragma unroll
  for (int tp = 0; tp < 8; ++tp) {
    step(sA, 2 * tp);
    step(sB, 2 * tp + 1);
  }

  pool0 += __shfl_down(pool0, 32);
  pool1 += __shfl_down(pool1, 32);
  if (lane < 32) {
    pool_lds0[wid][lane] = pool0;
    pool_lds1[wid][lane] = pool1;
  }

  for (int w = 0; w < 4; ++w) {
    __syncthreads();
    if (wid == w) {
#pragma unroll
      for (int r = 0; r < 16; ++r) {
        // verified C/D layout (32x32 MFMA): col=lane&31, row=(r&3)+8*(r>>2)+4*(lane>>5)
        const int i = (r & 3) + 8 * (r >> 2) + 4 * lhi;
        const int j = l31;
        if (w == 0) {
          corr_s[i][j]           = acc00[r];
          corr_s[i][j + 32]      = acc01[r];
          corr_s[j + 32][i]      = acc01[r];   // symmetric mirror
          corr_s[i + 32][j + 32] = acc11[r];
        } else {
          corr_s[i][j]           += acc00[r];
          corr_s[i][j + 32]      += acc01[r];
          corr_s[j + 32][i]      += acc01[r];
          corr_s[i + 32][j + 32] += acc11[r];
        }
      }
    }
  }
  __syncthreads();

  if (tid < Cn) {
    const float* wr = Wrow + tid * Cn;
    float so = 0.f;
#pragma unroll 8
    for (int d = 0; d < Cn; ++d) so += corr_s[tid][d] * wr[d];
    float pp = 0.f;
    if (tid < 32) {
#pragma unroll
      for (int w = 0; w < 4; ++w) pp += pool_lds0[w][tid];
    } else {
#pragma unroll
      for (int w = 0; w < 4; ++w) pp += pool_lds1[w][tid - 32];
    }
    float* o = part + (size_t)(b * Sn + s) * (2 * Cn);
    o[tid]      = so;
    o[Cn + tid] = pp;
  }
}

// ---------------------------------------------------------------------------
// Kernel 2: per-batch reduce partials + tiny MLP -> gate g[b,c]
// ---------------------------------------------------------------------------
__global__ __launch_bounds__(64) void se_kernel(
    const float* __restrict__ part, const float* __restrict__ brow,
    const float* __restrict__ W1, const float* __restrict__ b1,
    const float* __restrict__ W2, const float* __restrict__ b2,
    float* __restrict__ g) {
  const int b = blockIdx.x;
  const int t = threadIdx.x;   // 0..63

  __shared__ float y_s[Cn];
  __shared__ float z_s[REDn];

  float so = 0.f, pl = 0.f;
  for (int s = 0; s < Sn; ++s) {
    const float* p = part + (size_t)(b * Sn + s) * (2 * Cn);
    so += p[t];
    pl += p[Cn + t];
  }
  y_s[t] = (so + pl) * (1.0f / (float)Nn) + brow[t];
  __syncthreads();

  if (t < REDn) {
    float z = b1[t];
#pragma unroll 8
    for (int c = 0; c < Cn; ++c) z += W1[t * Cn + c] * y_s[c];
    z_s[t] = fmaxf(z, 0.f);
  }
  __syncthreads();

  float a = b2[t];
#pragma unroll
  for (int r = 0; r < REDn; ++r) a += W2[t * REDn + r] * z_s[r];
  g[b * Cn + t] = 1.0f / (1.0f + expf(-a));
}

// ---------------------------------------------------------------------------
// Kernel 3: out[b,c,n] = x[b,c,n] * g[b,c]
// 4096 blocks (8/CU, 32 waves/CU). Register double-buffer: next group's 4
// loads issue BEFORE this group's 4 stores, so the vmcnt wait for loads never
// forces store retirement. Nontemporal stores for the pure write stream.
// ---------------------------------------------------------------------------
#define SGRID 4096
__global__ __launch_bounds__(256) void scale_kernel(
    const float* __restrict__ x, const float* __restrict__ g,
    float* __restrict__ out) {
  __shared__ float g_lds[Bn * Cn];
  for (int i = threadIdx.x; i < Bn * Cn; i += 256) g_lds[i] = g[i];
  __syncthreads();

  const f32x4* xv = (const f32x4*)x;
  f32x4*       ov = (f32x4*)out;
  const size_t stride = (size_t)SGRID * 256;              // 1048576
  const size_t base   = (size_t)blockIdx.x * 256 + threadIdx.x;
  const int    gbase  = (int)(base >> 14);                // 16384 float4/(b,c)
  // total float4 = 16777216 = 16 * stride -> 4 groups of 4
  f32x4 v0 = xv[base];
  f32x4 v1 = xv[base + stride];
  f32x4 v2 = xv[base + 2 * stride];
  f32x4 v3 = xv[base + 3 * stride];
#pragma unroll
  for (int it = 0; it < 4; ++it) {
    const size_t cur = base + (size_t)(4 * it) * stride;
    const int    g0  = gbase + 256 * it;   // stride>>14 == 64 exactly
    f32x4 w0 = v0, w1 = v1, w2 = v2, w3 = v3;
    if (it < 3) {
      const size_t nxt = cur + 4 * stride;
      v0 = xv[nxt];
      v1 = xv[nxt + stride];
      v2 = xv[nxt + 2 * stride];
      v3 = xv[nxt + 3 * stride];
    }
    w0 *= g_lds[g0];
    w1 *= g_lds[g0 + 64];
    w2 *= g_lds[g0 + 128];
    w3 *= g_lds[g0 + 192];
    __builtin_nontemporal_store(w0, &ov[cur]);
    __builtin_nontemporal_store(w1, &ov[cur + stride]);
    __builtin_nontemporal_store(w2, &ov[cur + 2 * stride]);
    __builtin_nontemporal_store(w3, &ov[cur + 3 * stride]);
  }
}

// ---------------------------------------------------------------------------
extern "C" void kernel_launch(void* const* d_in, const int* in_sizes, int n_in,
                              void* d_out, int out_size, void* d_ws, size_t ws_size,
                              hipStream_t stream) {
  const float* x    = (const float*)d_in[0];
  const float* Wrow = (const float*)d_in[1];
  const float* brow = (const float*)d_in[2];
  const float* W1   = (const float*)d_in[3];
  const float* b1   = (const float*)d_in[4];
  const float* W2   = (const float*)d_in[5];
  const float* b2   = (const float*)d_in[6];
  float* out = (float*)d_out;

  // partials in the FRONT of d_out (512 KB, fully overwritten by scale);
  // gate g (4 KB) in d_ws.
  float* part = (float*)d_out;
  float* g    = (float*)d_ws;

  gram_pool_kernel<<<Bn * Sn, 256, 0, stream>>>(x, Wrow, part);
  se_kernel<<<Bn, 64, 0, stream>>>(part, brow, W1, b1, W2, b2, g);
  scale_kernel<<<SGRID, 256, 0, stream>>>(x, g, out);
}

// Round 11
// 152.897 us; speedup vs baseline: 1.8786x; 1.0365x over previous
//
#include <hip/hip_runtime.h>
#include <math.h>

// Problem constants (from reference)
#define Bn   16
#define Cn   64
#define Nn   65536        // H*W = 256*256
#define Sn   64           // n-slices per batch for gram kernel
#define Ln   (Nn / Sn)    // 1024 k-elements per block (256 per wave)
#define REDn 16

typedef float    f32x4  __attribute__((ext_vector_type(4)));
typedef float    f32x16 __attribute__((ext_vector_type(16)));
typedef __fp16   fp16x2 __attribute__((ext_vector_type(2)));
typedef _Float16 f16x8  __attribute__((ext_vector_type(8)));

union half8_u {
  f16x8  v;
  fp16x2 h[4];
};

// ---------------------------------------------------------------------------
// Kernel 1: per (batch, n-slice) block:
//   so_part[c]   = sum_d (sum_{n in slice} x[b,c,n]*x[b,d,n]) * Wrow[c,d]
//   pool_part[c] = sum_{n in slice} x[b,c,n]
// Coalesced global loads into WAVE-PRIVATE LDS buffers (no main-loop barriers),
// 2-tile register prefetch; MFMA fragments via padded conflict-free ds_read.
// (Proven correct+fast in R5/R10.)
// ---------------------------------------------------------------------------
__global__ __launch_bounds__(256, 4) void gram_pool_kernel(
    const float* __restrict__ x, const float* __restrict__ Wrow,
    float* __restrict__ part) {
  const int b    = blockIdx.x / Sn;
  const int s    = blockIdx.x % Sn;
  const int tid  = threadIdx.x;
  const int wid  = tid >> 6;
  const int lane = tid & 63;
  const int l31  = lane & 31;
  const int lhi  = lane >> 5;
  const int rr   = lane >> 2;   // staging row-within-group (0..15)
  const int cc   = lane & 3;    // staging 16B chunk (0..3)

  const float* xb = x + (size_t)b * Cn * Nn;

  __shared__ float stage[4][Cn * 17];   // per-wave [64 rows][17] f32 (pad)
  __shared__ float corr_s[Cn][Cn + 1];
  __shared__ float pool_lds0[4][32];
  __shared__ float pool_lds1[4][32];

  float* wb = &stage[wid][0];

  const float* gsrc[4];
  int widx[4];
#pragma unroll
  for (int i = 0; i < 4; ++i) {
    const int row = 16 * i + rr;
    gsrc[i] = xb + (size_t)row * Nn + cc * 4;
    widx[i] = row * 17 + cc * 4;
  }
  const int fA = l31 * 17 + lhi * 8;          // rows 0..31
  const int fB = (l31 + 32) * 17 + lhi * 8;   // rows 32..63

  const int kw = s * Ln + wid * (Ln / 4);     // wave's k base; 16 tiles of 16

  f32x16 acc00, acc01, acc11;
#pragma unroll
  for (int r = 0; r < 16; ++r) { acc00[r] = 0.f; acc01[r] = 0.f; acc11[r] = 0.f; }
  float pool0 = 0.f, pool1 = 0.f;

  f32x4 sA[4], sB[4];
#pragma unroll
  for (int i = 0; i < 4; ++i) sA[i] = *(const f32x4*)(gsrc[i] + kw);
#pragma unroll
  for (int i = 0; i < 4; ++i) sB[i] = *(const f32x4*)(gsrc[i] + kw + 16);

  auto step = [&](f32x4* stg, int t) {
#pragma unroll
    for (int i = 0; i < 4; ++i) *(f32x4*)&wb[widx[i]] = stg[i];
    if (t < 14) {
      const int ko = kw + (t + 2) * 16;
#pragma unroll
      for (int i = 0; i < 4; ++i) stg[i] = *(const f32x4*)(gsrc[i] + ko);
    }
    f32x4 a0 = *(const f32x4*)&wb[fA];
    f32x4 a1 = *(const f32x4*)&wb[fA + 4];
    f32x4 c0 = *(const f32x4*)&wb[fB];
    f32x4 c1 = *(const f32x4*)&wb[fB + 4];

    pool0 += (a0[0] + a0[1]) + (a0[2] + a0[3]) + (a1[0] + a1[1]) + (a1[2] + a1[3]);
    pool1 += (c0[0] + c0[1]) + (c0[2] + c0[3]) + (c1[0] + c1[1]) + (c1[2] + c1[3]);

    half8_u au, bu;
    au.h[0] = __builtin_amdgcn_cvt_pkrtz(a0[0], a0[1]);
    au.h[1] = __builtin_amdgcn_cvt_pkrtz(a0[2], a0[3]);
    au.h[2] = __builtin_amdgcn_cvt_pkrtz(a1[0], a1[1]);
    au.h[3] = __builtin_amdgcn_cvt_pkrtz(a1[2], a1[3]);
    bu.h[0] = __builtin_amdgcn_cvt_pkrtz(c0[0], c0[1]);
    bu.h[1] = __builtin_amdgcn_cvt_pkrtz(c0[2], c0[3]);
    bu.h[2] = __builtin_amdgcn_cvt_pkrtz(c1[0], c1[1]);
    bu.h[3] = __builtin_amdgcn_cvt_pkrtz(c1[2], c1[3]);

    acc00 = __builtin_amdgcn_mfma_f32_32x32x16_f16(au.v, au.v, acc00, 0, 0, 0);
    acc01 = __builtin_amdgcn_mfma_f32_32x32x16_f16(au.v, bu.v, acc01, 0, 0, 0);
    acc11 = __builtin_amdgcn_mfma_f32_32x32x16_f16(bu.v, bu.v, acc11, 0, 0, 0);
  };

#pragma unroll
  for (int tp = 0; tp < 8; ++tp) {
    step(sA, 2 * tp);
    step(sB, 2 * tp + 1);
  }

  pool0 += __shfl_down(pool0, 32);
  pool1 += __shfl_down(pool1, 32);
  if (lane < 32) {
    pool_lds0[wid][lane] = pool0;
    pool_lds1[wid][lane] = pool1;
  }

  for (int w = 0; w < 4; ++w) {
    __syncthreads();
    if (wid == w) {
#pragma unroll
      for (int r = 0; r < 16; ++r) {
        // verified C/D layout (32x32 MFMA): col=lane&31, row=(r&3)+8*(r>>2)+4*(lane>>5)
        const int i = (r & 3) + 8 * (r >> 2) + 4 * lhi;
        const int j = l31;
        if (w == 0) {
          corr_s[i][j]           = acc00[r];
          corr_s[i][j + 32]      = acc01[r];
          corr_s[j + 32][i]      = acc01[r];   // symmetric mirror
          corr_s[i + 32][j + 32] = acc11[r];
        } else {
          corr_s[i][j]           += acc00[r];
          corr_s[i][j + 32]      += acc01[r];
          corr_s[j + 32][i]      += acc01[r];
          corr_s[i + 32][j + 32] += acc11[r];
        }
      }
    }
  }
  __syncthreads();

  if (tid < Cn) {
    const float* wr = Wrow + tid * Cn;
    float so = 0.f;
#pragma unroll 8
    for (int d = 0; d < Cn; ++d) so += corr_s[tid][d] * wr[d];
    float pp = 0.f;
    if (tid < 32) {
#pragma unroll
      for (int w = 0; w < 4; ++w) pp += pool_lds0[w][tid];
    } else {
#pragma unroll
      for (int w = 0; w < 4; ++w) pp += pool_lds1[w][tid - 32];
    }
    float* o = part + (size_t)(b * Sn + s) * (2 * Cn);
    o[tid]      = so;
    o[Cn + tid] = pp;
  }
}

// ---------------------------------------------------------------------------
// Kernel 2: per-batch reduce partials + tiny MLP -> gate g[b,c]
// ---------------------------------------------------------------------------
__global__ __launch_bounds__(64) void se_kernel(
    const float* __restrict__ part, const float* __restrict__ brow,
    const float* __restrict__ W1, const float* __restrict__ b1,
    const float* __restrict__ W2, const float* __restrict__ b2,
    float* __restrict__ g) {
  const int b = blockIdx.x;
  const int t = threadIdx.x;   // 0..63

  __shared__ float y_s[Cn];
  __shared__ float z_s[REDn];

  float so = 0.f, pl = 0.f;
  for (int s = 0; s < Sn; ++s) {
    const float* p = part + (size_t)(b * Sn + s) * (2 * Cn);
    so += p[t];
    pl += p[Cn + t];
  }
  y_s[t] = (so + pl) * (1.0f / (float)Nn) + brow[t];
  __syncthreads();

  if (t < REDn) {
    float z = b1[t];
#pragma unroll 8
    for (int c = 0; c < Cn; ++c) z += W1[t * Cn + c] * y_s[c];
    z_s[t] = fmaxf(z, 0.f);
  }
  __syncthreads();

  float a = b2[t];
#pragma unroll
  for (int r = 0; r < REDn; ++r) a += W2[t * REDn + r] * z_s[r];
  g[b * Cn + t] = 1.0f / (1.0f + expf(-a));
}

// ---------------------------------------------------------------------------
// Kernel 3: out[b,c,n] = x[b,c,n] * g[b,c]
// Each block owns ONE contiguous 64KB region inside a single (b,c) plane:
//   - g is wave-uniform (one scalar load, no LDS)
//   - reads/writes fully contiguous -> max DRAM row / L2 sector locality
// Load-ahead register double-buffer; NT stores (out never re-read).
// ---------------------------------------------------------------------------
#define SGRID 4096        // 16384 float4 per (b,c) / 4096 per block = 4 blocks/plane
__global__ __launch_bounds__(256) void scale_kernel(
    const float* __restrict__ x, const float* __restrict__ g,
    float* __restrict__ out) {
  const int    bid   = blockIdx.x;
  const size_t base4 = (size_t)bid * 4096;   // float4 index of block's region
  const float  gg    = g[bid >> 2];          // region lies in one (b,c) plane

  const f32x4* xv = (const f32x4*)x + base4;
  f32x4*       ov = (f32x4*)out + base4;
  const int t = threadIdx.x;

  // 4096 float4 per block = 16/thread: 4 groups of 4, load-ahead pipeline
  f32x4 v0 = xv[t];
  f32x4 v1 = xv[t + 256];
  f32x4 v2 = xv[t + 512];
  f32x4 v3 = xv[t + 768];
#pragma unroll
  for (int it = 0; it < 4; ++it) {
    const int cur = t + it * 1024;
    f32x4 w0 = v0, w1 = v1, w2 = v2, w3 = v3;
    if (it < 3) {
      const int nxt = cur + 1024;
      v0 = xv[nxt];
      v1 = xv[nxt + 256];
      v2 = xv[nxt + 512];
      v3 = xv[nxt + 768];
    }
    w0 *= gg; w1 *= gg; w2 *= gg; w3 *= gg;
    __builtin_nontemporal_store(w0, &ov[cur]);
    __builtin_nontemporal_store(w1, &ov[cur + 256]);
    __builtin_nontemporal_store(w2, &ov[cur + 512]);
    __builtin_nontemporal_store(w3, &ov[cur + 768]);
  }
}

// ---------------------------------------------------------------------------
extern "C" void kernel_launch(void* const* d_in, const int* in_sizes, int n_in,
                              void* d_out, int out_size, void* d_ws, size_t ws_size,
                              hipStream_t stream) {
  const float* x    = (const float*)d_in[0];
  const float* Wrow = (const float*)d_in[1];
  const float* brow = (const float*)d_in[2];
  const float* W1   = (const float*)d_in[3];
  const float* b1   = (const float*)d_in[4];
  const float* W2   = (const float*)d_in[5];
  const float* b2   = (const float*)d_in[6];
  float* out = (float*)d_out;

  // partials in the FRONT of d_out (512 KB, fully overwritten by scale);
  // gate g (4 KB) in d_ws.
  float* part = (float*)d_out;
  float* g    = (float*)d_ws;

  gram_pool_kernel<<<Bn * Sn, 256, 0, stream>>>(x, Wrow, part);
  se_kernel<<<Bn, 64, 0, stream>>>(part, brow, W1, b1, W2, b2, g);
  scale_kernel<<<SGRID, 256, 0, stream>>>(x, g, out);
}